// Round 5
// baseline (273.431 us; speedup 1.0000x reference)
//
#include <hip/hip_runtime.h>

// WaveletParsingLayer: per-row stable stream compaction.
// x3[B,C,L] -> out[B,C,KEEP], dropping elements == FILLER (10.1f), order-preserving.
// x1, x2 unused.
//
// R5: R2-R4 post-mortem — three structurally different single-kernel variants
// (serial barriers / register-resident / LDS-staged coalesced stores) all pin
// at ~80 us with every pipe idle (VALU 13%, HBM 26%, occupancy 23-64% with no
// effect). Split into two dispatches to localize the bottleneck AND remove all
// intra-kernel serialization:
//   pass1: count survivors per (row, chunk1024, wave), 64-lane shfl exclusive
//          prefix per row -> 64 base ints/row in d_ws. Pure-read kernel.
//   pass2: 4 blocks per row (quarter-row each), ZERO barriers / ZERO LDS,
//          re-read x3 (LLC-warm), ballot prefix + precomputed base, scatter.
// Stream ordering between dispatches gives grid-wide completion + L2 coherence.

#define FILLER_VAL 10.1f
constexpr int L_LEN    = 16384;
constexpr int KEEP_LEN = 12288;
constexpr int BLOCK    = 256;            // 4 waves of 64
constexpr int NW       = BLOCK / 64;     // 4 waves per block
constexpr int CHUNK    = BLOCK * 4;      // 1024 elements per chunk
constexpr int NC       = L_LEN / CHUNK;  // 16 chunks per row
constexpr int NSEG     = NC * NW;        // 64 (chunk,wave) segments per row

// ---------------- Pass 1: per-segment survivor counts + row-local prefix ----
__global__ __launch_bounds__(BLOCK) void count_kernel(
    const float* __restrict__ x3, int* __restrict__ bases)
{
    const int row = blockIdx.x;
    const float* __restrict__ in = x3 + (size_t)row * L_LEN;

    const int tid  = threadIdx.x;
    const int lane = tid & 63;
    const int wid  = tid >> 6;

    __shared__ int cnt[NSEG];   // [chunk*NW + wave]

    #pragma unroll
    for (int c = 0; c < NC; ++c) {
        float4 v = *reinterpret_cast<const float4*>(in + c * CHUNK + tid * 4);
        unsigned long long m0 = __ballot(v.x != FILLER_VAL);
        unsigned long long m1 = __ballot(v.y != FILLER_VAL);
        unsigned long long m2 = __ballot(v.z != FILLER_VAL);
        unsigned long long m3 = __ballot(v.w != FILLER_VAL);
        if (lane == 0)
            cnt[c * NW + wid] = __popcll(m0) + __popcll(m1)
                              + __popcll(m2) + __popcll(m3);
    }
    __syncthreads();

    // Wave 0: 64-lane exclusive prefix over the 64 segment counts.
    if (tid < 64) {
        int own = cnt[tid];
        int x = own;
        #pragma unroll
        for (int d = 1; d < 64; d <<= 1) {
            int y = __shfl_up(x, d);
            if (lane >= d) x += y;
        }
        bases[row * NSEG + tid] = x - own;   // exclusive prefix
    }
}

// ---------------- Pass 2: quarter-row blocks, no barriers, scatter ----------
__global__ __launch_bounds__(BLOCK) void scatter_kernel(
    const float* __restrict__ x3, const int* __restrict__ bases,
    float* __restrict__ out)
{
    const int bid = blockIdx.x;
    const int row = bid >> 2;
    const int q   = bid & 3;

    const float* __restrict__ in = x3 + (size_t)row * L_LEN;
    float* __restrict__ o = out + (size_t)row * KEEP_LEN;
    const int* __restrict__ rb = bases + row * NSEG;

    const int tid  = threadIdx.x;
    const int lane = tid & 63;
    const int wid  = tid >> 6;
    const unsigned long long lt = (1ULL << lane) - 1ULL;

    #pragma unroll
    for (int i = 0; i < NC / 4; ++i) {
        const int c = q * (NC / 4) + i;
        float4 v = *reinterpret_cast<const float4*>(in + c * CHUNK + tid * 4);

        unsigned long long m0 = __ballot(v.x != FILLER_VAL);
        unsigned long long m1 = __ballot(v.y != FILLER_VAL);
        unsigned long long m2 = __ballot(v.z != FILLER_VAL);
        unsigned long long m3 = __ballot(v.w != FILLER_VAL);

        const int before = __popcll(m0 & lt) + __popcll(m1 & lt)
                         + __popcll(m2 & lt) + __popcll(m3 & lt);

        int pos = rb[c * NW + wid] + before;   // wave-uniform base + lane prefix

        if (v.x != FILLER_VAL) { if (pos < KEEP_LEN) o[pos] = v.x; ++pos; }
        if (v.y != FILLER_VAL) { if (pos < KEEP_LEN) o[pos] = v.y; ++pos; }
        if (v.z != FILLER_VAL) { if (pos < KEEP_LEN) o[pos] = v.z; ++pos; }
        if (v.w != FILLER_VAL) { if (pos < KEEP_LEN) o[pos] = v.w; ++pos; }
    }
}

extern "C" void kernel_launch(void* const* d_in, const int* in_sizes, int n_in,
                              void* d_out, int out_size, void* d_ws, size_t ws_size,
                              hipStream_t stream)
{
    // in order: x1 [B,C,4096] f32 (unused), x2 [B,C,4096] f32 (unused),
    //           x3 [B,C,L] f32, keep_len (scalar int, value 12288)
    const float* x3 = (const float*)d_in[2];
    float* out = (float*)d_out;
    int* bases = (int*)d_ws;                 // rows * 64 ints = 512 KB << ws_size

    const int rows = in_sizes[2] / L_LEN;    // B*C = 2048

    count_kernel<<<rows, BLOCK, 0, stream>>>(x3, bases);
    scatter_kernel<<<rows * 4, BLOCK, 0, stream>>>(x3, bases, out);
}

// Round 6
// 269.552 us; speedup vs baseline: 1.0144x; 1.0144x over previous
//
#include <hip/hip_runtime.h>

// WaveletParsingLayer: per-row stable stream compaction.
// x3[B,C,L] -> out[B,C,KEEP], dropping elements == FILLER (10.1f), order-preserving.
// x1, x2 unused.
//
// R6: R5 localized the bottleneck — pure-read pass ran at ~5.4 TB/s while the
// scatter-store pass ran at ~3.8 TB/s; R4 (coalesced stores, 2048 blocks,
// 2-barrier serial body) stayed at 80 us. Combine BOTH levers:
//   * 8192 blocks (quarter-row each) -> ~8 resident blocks/CU, deep MLP
//   * zero inter-block communication: each block redundantly counts survivors
//     in its row's PRECEDING quarters (sibling blocks touch the same lines at
//     the same time -> L2/LLC-hot; ~1.5x logical read amp, ~0 extra HBM)
//   * own quarter compacted into a 16 KB LDS stage, then emitted as
//     CONSECUTIVE coalesced scalar stores (full 64B lines, no gaps)

#define FILLER_VAL 10.1f
constexpr int L_LEN    = 16384;
constexpr int KEEP_LEN = 12288;
constexpr int BLOCK    = 256;              // 4 waves of 64
constexpr int NW       = BLOCK / 64;       // 4 waves
constexpr int QELEM    = 4096;             // elements per block (quarter row)
constexpr int QCH      = QELEM / (BLOCK * 4);  // 4 load iterations per quarter
constexpr int NQ       = L_LEN / QELEM;    // 4 quarters per row

__global__ __launch_bounds__(BLOCK) void compact_quarters(
    const float* __restrict__ x3, float* __restrict__ out)
{
    const int bid = blockIdx.x;
    const int row = bid >> 2;           // NQ = 4
    const int q   = bid & 3;

    const float* __restrict__ in = x3 + (size_t)row * L_LEN;
    float* __restrict__ o = out + (size_t)row * KEEP_LEN;

    const int tid  = threadIdx.x;
    const int lane = tid & 63;
    const int wid  = tid >> 6;
    const unsigned long long lt = (1ULL << lane) - 1ULL;

    __shared__ float stage[QELEM];      // 16 KB survivor staging (cnt <= 4096)
    __shared__ int   segCnt[QCH][NW];   // own-quarter per-(iter,wave) counts
    __shared__ int   preW[NW];          // per-wave counts over preceding quarters

    // ---- Own-quarter loads first (critical path), fully coalesced 16B.
    float4 v[QCH];
    #pragma unroll
    for (int c = 0; c < QCH; ++c)
        v[c] = *reinterpret_cast<const float4*>(
                   in + q * QELEM + c * (BLOCK * 4) + tid * 4);

    // ---- Phase A: redundant count of preceding quarters (LLC-hot reads).
    int pre = 0;   // wave-uniform
    for (int p = 0; p < q; ++p) {
        #pragma unroll
        for (int c = 0; c < QCH; ++c) {
            float4 u = *reinterpret_cast<const float4*>(
                           in + p * QELEM + c * (BLOCK * 4) + tid * 4);
            unsigned long long m0 = __ballot(u.x != FILLER_VAL);
            unsigned long long m1 = __ballot(u.y != FILLER_VAL);
            unsigned long long m2 = __ballot(u.z != FILLER_VAL);
            unsigned long long m3 = __ballot(u.w != FILLER_VAL);
            pre += __popcll(m0) + __popcll(m1) + __popcll(m2) + __popcll(m3);
        }
    }
    if (lane == 0) preW[wid] = pre;

    // ---- Phase B: own-quarter ballots. Element order within quarter:
    // idx = c*1024 + wid*256 + lane*4 + j  -> segment s = c*NW + wid.
    int before[QCH];
    #pragma unroll
    for (int c = 0; c < QCH; ++c) {
        unsigned long long m0 = __ballot(v[c].x != FILLER_VAL);
        unsigned long long m1 = __ballot(v[c].y != FILLER_VAL);
        unsigned long long m2 = __ballot(v[c].z != FILLER_VAL);
        unsigned long long m3 = __ballot(v[c].w != FILLER_VAL);
        before[c] = __popcll(m0 & lt) + __popcll(m1 & lt)
                  + __popcll(m2 & lt) + __popcll(m3 & lt);
        if (lane == 0)
            segCnt[c][wid] = __popcll(m0) + __popcll(m1)
                           + __popcll(m2) + __popcll(m3);
    }
    __syncthreads();   // barrier 1: preW + segCnt visible

    // Block's output base within the row = survivors in preceding quarters.
    int base = 0;
    #pragma unroll
    for (int w = 0; w < NW; ++w) base += preW[w];

    // Per-(iter,wave) segment bases within the block.
    int run = 0;
    int myseg[QCH];
    #pragma unroll
    for (int c = 0; c < QCH; ++c) {
        int wb = run;
        #pragma unroll
        for (int w = 0; w < NW; ++w) {
            int t = segCnt[c][w];
            if (w < wid) wb += t;
            run += t;
        }
        myseg[c] = wb;
    }
    const int cnt_total = run;   // survivors in this quarter (<= QELEM)

    // ---- Scatter own survivors into LDS stage (near-consecutive -> ~2-way).
    #pragma unroll
    for (int c = 0; c < QCH; ++c) {
        int pos = myseg[c] + before[c];
        if (v[c].x != FILLER_VAL) { if (pos < QELEM) stage[pos] = v[c].x; ++pos; }
        if (v[c].y != FILLER_VAL) { if (pos < QELEM) stage[pos] = v[c].y; ++pos; }
        if (v[c].z != FILLER_VAL) { if (pos < QELEM) stage[pos] = v[c].z; ++pos; }
        if (v[c].w != FILLER_VAL) { if (pos < QELEM) stage[pos] = v[c].w; ++pos; }
    }
    __syncthreads();   // barrier 2: stage complete

    // ---- Coalesced copy-out: consecutive scalar stores (full 64B lines).
    int gend = base + cnt_total;
    if (gend > KEEP_LEN) gend = KEEP_LEN;   // safety clamp
    for (int i = base + tid; i < gend; i += BLOCK)
        o[i] = stage[i - base];
}

extern "C" void kernel_launch(void* const* d_in, const int* in_sizes, int n_in,
                              void* d_out, int out_size, void* d_ws, size_t ws_size,
                              hipStream_t stream)
{
    // in order: x1 [B,C,4096] f32 (unused), x2 [B,C,4096] f32 (unused),
    //           x3 [B,C,L] f32, keep_len (scalar int, value 12288)
    const float* x3 = (const float*)d_in[2];
    float* out = (float*)d_out;

    const int rows = in_sizes[2] / L_LEN;   // B*C = 2048

    compact_quarters<<<rows * NQ, BLOCK, 0, stream>>>(x3, out);
}